// Round 13
// baseline (876.027 us; speedup 1.0000x reference)
//
#include <hip/hip_runtime.h>

#define DIMS 128
#define KTOP 16
#define SMAX 2048     // max MAXG supported by top-k kernel
#define SLICE 128     // candidates per score block (1 per thread)
#define QT 16         // queries per chunk (LDS-resident)
#define NTHR 128

__device__ __forceinline__ unsigned long long packsim(float v, int g) {
    unsigned u = __float_as_uint(v);
    u = (u & 0x80000000u) ? ~u : (u | 0x80000000u);
    return ((unsigned long long)u << 32) | (unsigned)(0xFFFFFFFFu - (unsigned)g);
}

// ---------------- Kernel 0: bucket queries by partition ----------------
__global__ __launch_bounds__(256)
void bucket_kernel(const int* __restrict__ hard_assign,
                   int* __restrict__ qcount, int* __restrict__ qlist, int B)
{
    const int b = blockIdx.x * 256 + threadIdx.x;
    if (b < B) {
        const int p = hard_assign[b];
        const int slot = atomicAdd(&qcount[p], 1);
        qlist[(size_t)p * B + slot] = b;
    }
}

// ---- Kernel 1: candidate-per-thread GEMV bundle. No key LDS, no shuffles. ----
// Thread owns one candidate row, streams it global->reg in 16-dim chunks
// (prefetch-1), FMAs against 16 LDS queries (uniform broadcast reads),
// thread-local norm. acc[16] per thread.
__global__ __launch_bounds__(NTHR)
void score_kernel(const float* __restrict__ query,
                  const float* __restrict__ keys,
                  const int*   __restrict__ cached_groups,
                  const int*   __restrict__ qcount,
                  const int*   __restrict__ qlist,
                  float* __restrict__ sims,
                  int B, int N, int MAXG, int nslice)
{
    __shared__ float s_q[QT][DIMS];   // 8 KB
    __shared__ int   s_qb[QT];

    const int p = blockIdx.x / nslice;
    const int s = blockIdx.x % nslice;
    const int cnt = qcount[p];
    if (cnt == 0) return;

    const int t = threadIdx.x;
    const int base = s * SLICE;
    const int* gp = cached_groups + (size_t)p * MAXG;
    const int* ql = qlist + (size_t)p * B;

    const int  cand   = (base + t < MAXG) ? gp[base + t] : -1;
    const int  sf     = cand < 0 ? 0 : (cand > N - 1 ? N - 1 : cand);
    const bool valid  = (cand >= 0);
    const bool haveslot = (base + t < MAXG);
    const float* kr = keys + (size_t)sf * DIMS;

    for (int qbase = 0; qbase < cnt; qbase += QT) {
        // ---- stage QT query rows into LDS: 512 float4s over 128 threads ----
        {
            #pragma unroll
            for (int i = 0; i < 4; ++i) {
                const int fidx = i * NTHR + t;       // 0..511
                const int q    = fidx >> 5;          // 32 float4 per row
                const int off  = (fidx & 31) * 4;
                const int ii   = qbase + q;
                const int sq   = ql[(ii < cnt) ? ii : (cnt - 1)];
                *(float4*)&s_q[q][off] = *(const float4*)(query + (size_t)sq * DIMS + off);
                if (fidx < QT && fidx + qbase < cnt + QT)  // thread 0..15 record ids
                    ;
            }
            if (t < QT) {
                const int ii = qbase + t;
                s_qb[t] = ql[(ii < cnt) ? ii : (cnt - 1)];
            }
        }
        __syncthreads();

        float acc[QT];
        #pragma unroll
        for (int q = 0; q < QT; ++q) acc[q] = 0.0f;
        float ks = 0.0f;

        float4 ka0 = *(const float4*)(kr + 0);
        float4 ka1 = *(const float4*)(kr + 4);
        float4 ka2 = *(const float4*)(kr + 8);
        float4 ka3 = *(const float4*)(kr + 12);

        #pragma unroll
        for (int dblk = 0; dblk < 8; ++dblk) {
            float4 kb0, kb1, kb2, kb3;
            if (dblk < 7) {                          // prefetch next 16 dims
                const float* nx = kr + (dblk + 1) * 16;
                kb0 = *(const float4*)(nx + 0);
                kb1 = *(const float4*)(nx + 4);
                kb2 = *(const float4*)(nx + 8);
                kb3 = *(const float4*)(nx + 12);
            }
            ks += ka0.x*ka0.x + ka0.y*ka0.y + ka0.z*ka0.z + ka0.w*ka0.w
                + ka1.x*ka1.x + ka1.y*ka1.y + ka1.z*ka1.z + ka1.w*ka1.w
                + ka2.x*ka2.x + ka2.y*ka2.y + ka2.z*ka2.z + ka2.w*ka2.w
                + ka3.x*ka3.x + ka3.y*ka3.y + ka3.z*ka3.z + ka3.w*ka3.w;
            const int d0 = dblk * 16;
            #pragma unroll
            for (int q = 0; q < QT; ++q) {
                const float4 q0 = *(const float4*)&s_q[q][d0 + 0];
                const float4 q1 = *(const float4*)&s_q[q][d0 + 4];
                const float4 q2 = *(const float4*)&s_q[q][d0 + 8];
                const float4 q3 = *(const float4*)&s_q[q][d0 + 12];
                acc[q] += ka0.x*q0.x + ka0.y*q0.y + ka0.z*q0.z + ka0.w*q0.w
                        + ka1.x*q1.x + ka1.y*q1.y + ka1.z*q1.z + ka1.w*q1.w
                        + ka2.x*q2.x + ka2.y*q2.y + ka2.z*q2.z + ka2.w*q2.w
                        + ka3.x*q3.x + ka3.y*q3.y + ka3.z*q3.z + ka3.w*q3.w;
            }
            ka0 = kb0; ka1 = kb1; ka2 = kb2; ka3 = kb3;
        }

        // ---- epilogue: thread-local norm, mask, coalesced scalar stores ----
        const float inv = 1.0f / fmaxf(sqrtf(ks), 1e-12f);
        if (haveslot) {
            #pragma unroll
            for (int q = 0; q < QT; ++q) {
                if (qbase + q < cnt) {
                    const int b = s_qb[q];
                    sims[(size_t)b * MAXG + base + t] =
                        valid ? acc[q] * inv : -1.0e9f;
                }
            }
        }

        if (qbase + QT < cnt) __syncthreads();   // protect s_q rewrite
    }
}

// ---------------- Kernel 2: top-16 per query + output gather ----------------
#define CASW(x,y) { if ((x) < (y)) { const unsigned long long _t = (x); (x) = (y); (y) = _t; } }

__global__ __launch_bounds__(256)
void topk_gather_kernel(const float* __restrict__ keys,
                        const float* __restrict__ vals,
                        const float* __restrict__ labels,
                        const int*   __restrict__ hard_assign,
                        const int*   __restrict__ cached_groups,
                        const int*   __restrict__ group_sizes,
                        const float* __restrict__ sims,
                        float* __restrict__ out,
                        int B, int MAXG)
{
    const int b = blockIdx.x, t = threadIdx.x;
    const int lane = t & 63, w = t >> 6;
    const int sub = t & 15, cg = t >> 4;

    __shared__ unsigned long long s_merge[64];
    __shared__ int s_wing[KTOP];

    const int p = hard_assign[b];
    const int grpsz = group_sizes[p];
    const bool normal = (grpsz >= KTOP);
    const int* gptr = cached_groups + (size_t)p * MAXG;
    const float* simrow = sims + (size_t)b * MAXG;

    // phase A: per-wave top-16 of 512, sorted-heads (keys globally unique)
    unsigned long long k0, k1, k2, k3, k4, k5, k6, k7;
    {
        #define LDK(j) ({ const int g = w * (SMAX / 4) + (j) * 64 + lane;          \
                          const float v = (g < MAXG) ? simrow[g] : -3.0e38f;       \
                          packsim(v, g); })
        k0 = LDK(0); k1 = LDK(1); k2 = LDK(2); k3 = LDK(3);
        k4 = LDK(4); k5 = LDK(5); k6 = LDK(6); k7 = LDK(7);
        #undef LDK
    }
    // Batcher odd-even mergesort, 19 comparators, descending
    CASW(k0,k1) CASW(k2,k3) CASW(k4,k5) CASW(k6,k7)
    CASW(k0,k2) CASW(k1,k3) CASW(k4,k6) CASW(k5,k7)
    CASW(k1,k2) CASW(k5,k6)
    CASW(k0,k4) CASW(k1,k5) CASW(k2,k6) CASW(k3,k7)
    CASW(k2,k4) CASW(k3,k5)
    CASW(k1,k2) CASW(k3,k4) CASW(k5,k6)

    #pragma unroll 1
    for (int r = 0; r < KTOP; ++r) {
        unsigned long long wm = k0;
        #pragma unroll
        for (int off = 1; off < 64; off <<= 1) {
            const unsigned long long o = __shfl_xor(wm, off, 64);
            wm = (o > wm) ? o : wm;
        }
        if (lane == 0) s_merge[w * KTOP + r] = wm;
        if (k0 == wm) {                  // unique keys -> exactly one winner
            k0 = k1; k1 = k2; k2 = k3; k3 = k4;
            k4 = k5; k5 = k6; k6 = k7; k7 = 0ull;
        }
    }
    __syncthreads();

    // phase B: wave 0 bitonic-sorts the 64 survivors (ascending); rank r at lane 63-r
    if (w == 0) {
        unsigned long long u = s_merge[lane];
        #pragma unroll
        for (int k = 2; k <= 64; k <<= 1) {
            #pragma unroll
            for (int j = k >> 1; j > 0; j >>= 1) {
                const unsigned long long o = __shfl_xor(u, j, 64);
                const bool low = (lane & j) == 0;
                const bool asc = (lane & k) == 0;
                const unsigned long long mn = (u < o) ? u : o;
                const unsigned long long mx = (u < o) ? o : u;
                u = (low == asc) ? mn : mx;
            }
        }
        if (lane >= 64 - KTOP)
            s_wing[63 - lane] = (int)(0xFFFFFFFFu - (unsigned)(u & 0xFFFFFFFFull));
    }
    __syncthreads();

    // outputs: group cg handles winner #cg
    const int g    = s_wing[cg];
    const int cand = gptr[g];
    const int idx  = cand < 0 ? 0 : cand;

    const size_t BK = (size_t)B * KTOP;
    float* out_nk = out;
    float* out_nv = out + BK * DIMS;
    float* out_nl = out + 2 * BK * DIMS;
    float* out_id = out_nl + BK;

    const size_t od = ((size_t)b * KTOP + cg) * DIMS + sub * 8;
    if (normal) {
        const float* kr = keys + (size_t)idx * DIMS + sub * 8;
        const float* vr = vals + (size_t)idx * DIMS + sub * 8;
        *(float4*)(out_nk + od)     = *(const float4*)(kr);
        *(float4*)(out_nk + od + 4) = *(const float4*)(kr + 4);
        *(float4*)(out_nv + od)     = *(const float4*)(vr);
        *(float4*)(out_nv + od + 4) = *(const float4*)(vr + 4);
        if (sub == 0) {
            out_nl[(size_t)b * KTOP + cg] = labels[idx];
            out_id[(size_t)b * KTOP + cg] = (float)idx;
        }
    } else {
        const float4 z = make_float4(0.f, 0.f, 0.f, 0.f);
        *(float4*)(out_nk + od)     = z;
        *(float4*)(out_nk + od + 4) = z;
        *(float4*)(out_nv + od)     = z;
        *(float4*)(out_nv + od + 4) = z;
        if (sub == 0) {
            out_nl[(size_t)b * KTOP + cg] = 0.0f;
            out_id[(size_t)b * KTOP + cg] = 0.0f;
        }
    }
}

extern "C" void kernel_launch(void* const* d_in, const int* in_sizes, int n_in,
                              void* d_out, int out_size, void* d_ws, size_t ws_size,
                              hipStream_t stream) {
    const float* query  = (const float*)d_in[0];
    const float* keys   = (const float*)d_in[1];
    const float* vals   = (const float*)d_in[2];
    const float* labels = (const float*)d_in[3];
    const int* hard_assign   = (const int*)d_in[4];
    const int* cached_groups = (const int*)d_in[5];
    const int* group_sizes   = (const int*)d_in[6];

    const int B = in_sizes[0] / DIMS;
    const int N = in_sizes[1] / DIMS;
    const int P = in_sizes[6];
    const int MAXG = in_sizes[5] / P;
    const int nslice = (MAXG + SLICE - 1) / SLICE;

    float* sims  = (float*)d_ws;                                // B*MAXG floats
    int* qcount  = (int*)((char*)d_ws + (size_t)B * MAXG * 4);  // P ints
    int* qlist   = qcount + P;                                  // P*B ints

    hipMemsetAsync(qcount, 0, P * sizeof(int), stream);

    bucket_kernel<<<(B + 255) / 256, 256, 0, stream>>>(hard_assign, qcount, qlist, B);

    score_kernel<<<P * nslice, NTHR, 0, stream>>>(
        query, keys, cached_groups, qcount, qlist, sims, B, N, MAXG, nslice);

    topk_gather_kernel<<<B, 256, 0, stream>>>(
        keys, vals, labels, hard_assign, cached_groups, group_sizes, sims,
        (float*)d_out, B, MAXG);
}

// Round 14
// 59.497 us; speedup vs baseline: 14.7238x; 14.7238x over previous
//
#include <hip/hip_runtime.h>

#define DIMS 128
#define KTOP 16
#define SMAX 2048     // max MAXG supported by top-k kernel
#define SLICE 64      // candidates per score block
#define CK 64         // s_keyT row stride in dwords (unpadded; 2-way = free)
#define CQ 16         // s_qT row stride in dwords
#define QT 16         // queries per chunk
#define NTHR 128

__device__ __forceinline__ unsigned long long packsim(float v, int g) {
    unsigned u = __float_as_uint(v);
    u = (u & 0x80000000u) ? ~u : (u | 0x80000000u);
    return ((unsigned long long)u << 32) | (unsigned)(0xFFFFFFFFu - (unsigned)g);
}

// ---------------- Kernel 0: bucket queries by partition ----------------
__global__ __launch_bounds__(256)
void bucket_kernel(const int* __restrict__ hard_assign,
                   int* __restrict__ qcount, int* __restrict__ qlist, int B)
{
    const int b = blockIdx.x * 256 + threadIdx.x;
    if (b < B) {
        const int p = hard_assign[b];
        const int slot = atomicAdd(&qcount[p], 1);
        qlist[(size_t)p * B + slot] = b;
    }
}

// ---- Kernel 1 (r10-proven): register-tiled GEMM, 16q x 64c per block ----
// 3 blocks/CU resident (40.6 KB LDS); thread tile 2q x 4c; no shuffles in loop.
__global__ __launch_bounds__(NTHR)
void score_kernel(const float* __restrict__ query,
                  const float* __restrict__ keys,
                  const int*   __restrict__ cached_groups,
                  const int*   __restrict__ qcount,
                  const int*   __restrict__ qlist,
                  float* __restrict__ sims,
                  int B, int N, int MAXG, int nslice)
{
    __shared__ float s_keyT[DIMS * CK];   // 32 KB, [d][c]
    __shared__ float s_qT[DIMS * CQ];     //  8 KB, [d][q]
    __shared__ float s_inv[SLICE];
    __shared__ int   s_g[SLICE];
    __shared__ int   s_qb[QT];

    const int p = blockIdx.x / nslice;
    const int s = blockIdx.x % nslice;
    const int cnt = qcount[p];
    if (cnt == 0) return;

    const int t = threadIdx.x;
    const int base = s * SLICE;
    const int* gp = cached_groups + (size_t)p * MAXG;
    const int* ql = qlist + (size_t)p * B;

    // ---- stage keys: 2 threads per candidate row (64 dims each) ----
    {
        const int r    = t >> 1;          // candidate 0..63
        const int half = t & 1;           // dim half
        const int cand = (base + r < MAXG) ? gp[base + r] : -1;
        if (half == 0) s_g[r] = cand;
        const int sf = cand < 0 ? 0 : (cand > N - 1 ? N - 1 : cand);
        const float* kr = keys + (size_t)sf * DIMS + half * 64;
        float ks = 0.0f;
        #pragma unroll
        for (int h = 0; h < 2; ++h) {     // 2 batches of 8 b128 loads (deep MLP)
            float4 v[8];
            #pragma unroll
            for (int i = 0; i < 8; ++i)
                v[i] = *(const float4*)(kr + h * 32 + i * 4);
            #pragma unroll
            for (int i = 0; i < 8; ++i) {
                const int d = half * 64 + h * 32 + i * 4;
                ks += v[i].x * v[i].x + v[i].y * v[i].y
                    + v[i].z * v[i].z + v[i].w * v[i].w;
                s_keyT[(d + 0) * CK + r] = v[i].x;
                s_keyT[(d + 1) * CK + r] = v[i].y;
                s_keyT[(d + 2) * CK + r] = v[i].z;
                s_keyT[(d + 3) * CK + r] = v[i].w;
            }
        }
        ks += __shfl_xor(ks, 1, 64);      // pair-reduce the two halves
        if (half == 0) s_inv[r] = 1.0f / fmaxf(sqrtf(ks), 1e-12f);
    }

    const int q0 = (t >> 4) * 2;          // 0,2,..,14
    const int c0 = (t & 15) * 4;          // 0,4,..,60

    for (int qbase = 0; qbase < cnt; qbase += QT) {
        // ---- stage QT query rows transposed: thread (q=t&15, dblk=t>>4) ----
        {
            const int q    = t & 15;
            const int dblk = t >> 4;      // 0..7, 16 dims each
            const int ii = qbase + q;
            const int sq = ql[(ii < cnt) ? ii : (cnt - 1)];   // dup tail, masked
            if (dblk == 0) s_qb[q] = sq;
            const float* qr = query + (size_t)sq * DIMS + dblk * 16;
            #pragma unroll
            for (int i = 0; i < 4; ++i) {
                const float4 v = *(const float4*)(qr + i * 4);
                const int d = dblk * 16 + i * 4;
                s_qT[(d + 0) * CQ + q] = v.x;
                s_qT[(d + 1) * CQ + q] = v.y;
                s_qT[(d + 2) * CQ + q] = v.z;
                s_qT[(d + 3) * CQ + q] = v.w;
            }
        }
        __syncthreads();   // first iter: also covers key staging

        float acc[2][4];
        #pragma unroll
        for (int a = 0; a < 2; ++a)
            #pragma unroll
            for (int bb = 0; bb < 4; ++bb) acc[a][bb] = 0.0f;

        // A-read: b64 broadcast (1 addr per quarter-wave); B-read: b128 2-way (free)
        #pragma unroll 8
        for (int k = 0; k < DIMS; ++k) {
            const float2 aq = *(const float2*)&s_qT[k * CQ + q0];
            const float4 bk = *(const float4*)&s_keyT[k * CK + c0];
            acc[0][0] += aq.x * bk.x; acc[0][1] += aq.x * bk.y;
            acc[0][2] += aq.x * bk.z; acc[0][3] += aq.x * bk.w;
            acc[1][0] += aq.y * bk.x; acc[1][1] += aq.y * bk.y;
            acc[1][2] += aq.y * bk.z; acc[1][3] += aq.y * bk.w;
        }

        // ---- epilogue: scale by key inv-norm, mask invalid, coalesced f4 ----
        const float4 inv = *(const float4*)&s_inv[c0];
        const int4   gv  = *(const int4*)&s_g[c0];
        #pragma unroll
        for (int qi = 0; qi < 2; ++qi) {
            const int ii = qbase + q0 + qi;
            if (ii < cnt) {
                const int b = s_qb[q0 + qi];
                float4 o;
                o.x = (gv.x >= 0) ? acc[qi][0] * inv.x : -1.0e9f;
                o.y = (gv.y >= 0) ? acc[qi][1] * inv.y : -1.0e9f;
                o.z = (gv.z >= 0) ? acc[qi][2] * inv.z : -1.0e9f;
                o.w = (gv.w >= 0) ? acc[qi][3] * inv.w : -1.0e9f;
                float* dst = sims + (size_t)b * MAXG + base + c0;
                if (base + c0 + 3 < MAXG) {
                    *(float4*)dst = o;
                } else {
                    if (base + c0 + 0 < MAXG) dst[0] = o.x;
                    if (base + c0 + 1 < MAXG) dst[1] = o.y;
                    if (base + c0 + 2 < MAXG) dst[2] = o.z;
                }
            }
        }

        if (qbase + QT < cnt) __syncthreads();   // protect s_qT rewrite
    }
}

// ---------------- Kernel 2: top-16 per query + output gather ----------------
#define CASW(x,y) { if ((x) < (y)) { const unsigned long long _t = (x); (x) = (y); (y) = _t; } }

__global__ __launch_bounds__(256)
void topk_gather_kernel(const float* __restrict__ keys,
                        const float* __restrict__ vals,
                        const float* __restrict__ labels,
                        const int*   __restrict__ hard_assign,
                        const int*   __restrict__ cached_groups,
                        const int*   __restrict__ group_sizes,
                        const float* __restrict__ sims,
                        float* __restrict__ out,
                        int B, int MAXG)
{
    const int b = blockIdx.x, t = threadIdx.x;
    const int lane = t & 63, w = t >> 6;
    const int sub = t & 15, cg = t >> 4;

    __shared__ unsigned long long s_merge[64];
    __shared__ int s_wing[KTOP];

    const int p = hard_assign[b];
    const int grpsz = group_sizes[p];
    const bool normal = (grpsz >= KTOP);
    const int* gptr = cached_groups + (size_t)p * MAXG;
    const float* simrow = sims + (size_t)b * MAXG;

    // phase A: per-wave top-16 of 512, sorted-heads (keys globally unique)
    unsigned long long k0, k1, k2, k3, k4, k5, k6, k7;
    {
        #define LDK(j) ({ const int g = w * (SMAX / 4) + (j) * 64 + lane;          \
                          const float v = (g < MAXG) ? simrow[g] : -3.0e38f;       \
                          packsim(v, g); })
        k0 = LDK(0); k1 = LDK(1); k2 = LDK(2); k3 = LDK(3);
        k4 = LDK(4); k5 = LDK(5); k6 = LDK(6); k7 = LDK(7);
        #undef LDK
    }
    // Batcher odd-even mergesort, 19 comparators, descending
    CASW(k0,k1) CASW(k2,k3) CASW(k4,k5) CASW(k6,k7)
    CASW(k0,k2) CASW(k1,k3) CASW(k4,k6) CASW(k5,k7)
    CASW(k1,k2) CASW(k5,k6)
    CASW(k0,k4) CASW(k1,k5) CASW(k2,k6) CASW(k3,k7)
    CASW(k2,k4) CASW(k3,k5)
    CASW(k1,k2) CASW(k3,k4) CASW(k5,k6)

    #pragma unroll 1
    for (int r = 0; r < KTOP; ++r) {
        unsigned long long wm = k0;
        #pragma unroll
        for (int off = 1; off < 64; off <<= 1) {
            const unsigned long long o = __shfl_xor(wm, off, 64);
            wm = (o > wm) ? o : wm;
        }
        if (lane == 0) s_merge[w * KTOP + r] = wm;
        if (k0 == wm) {                  // unique keys -> exactly one winner
            k0 = k1; k1 = k2; k2 = k3; k3 = k4;
            k4 = k5; k5 = k6; k6 = k7; k7 = 0ull;
        }
    }
    __syncthreads();

    // phase B: wave 0 bitonic-sorts the 64 survivors (ascending); rank r at lane 63-r
    if (w == 0) {
        unsigned long long u = s_merge[lane];
        #pragma unroll
        for (int k = 2; k <= 64; k <<= 1) {
            #pragma unroll
            for (int j = k >> 1; j > 0; j >>= 1) {
                const unsigned long long o = __shfl_xor(u, j, 64);
                const bool low = (lane & j) == 0;
                const bool asc = (lane & k) == 0;
                const unsigned long long mn = (u < o) ? u : o;
                const unsigned long long mx = (u < o) ? o : u;
                u = (low == asc) ? mn : mx;
            }
        }
        if (lane >= 64 - KTOP)
            s_wing[63 - lane] = (int)(0xFFFFFFFFu - (unsigned)(u & 0xFFFFFFFFull));
    }
    __syncthreads();

    // outputs: group cg handles winner #cg
    const int g    = s_wing[cg];
    const int cand = gptr[g];
    const int idx  = cand < 0 ? 0 : cand;

    const size_t BK = (size_t)B * KTOP;
    float* out_nk = out;
    float* out_nv = out + BK * DIMS;
    float* out_nl = out + 2 * BK * DIMS;
    float* out_id = out_nl + BK;

    const size_t od = ((size_t)b * KTOP + cg) * DIMS + sub * 8;
    if (normal) {
        const float* kr = keys + (size_t)idx * DIMS + sub * 8;
        const float* vr = vals + (size_t)idx * DIMS + sub * 8;
        *(float4*)(out_nk + od)     = *(const float4*)(kr);
        *(float4*)(out_nk + od + 4) = *(const float4*)(kr + 4);
        *(float4*)(out_nv + od)     = *(const float4*)(vr);
        *(float4*)(out_nv + od + 4) = *(const float4*)(vr + 4);
        if (sub == 0) {
            out_nl[(size_t)b * KTOP + cg] = labels[idx];
            out_id[(size_t)b * KTOP + cg] = (float)idx;
        }
    } else {
        const float4 z = make_float4(0.f, 0.f, 0.f, 0.f);
        *(float4*)(out_nk + od)     = z;
        *(float4*)(out_nk + od + 4) = z;
        *(float4*)(out_nv + od)     = z;
        *(float4*)(out_nv + od + 4) = z;
        if (sub == 0) {
            out_nl[(size_t)b * KTOP + cg] = 0.0f;
            out_id[(size_t)b * KTOP + cg] = 0.0f;
        }
    }
}

extern "C" void kernel_launch(void* const* d_in, const int* in_sizes, int n_in,
                              void* d_out, int out_size, void* d_ws, size_t ws_size,
                              hipStream_t stream) {
    const float* query  = (const float*)d_in[0];
    const float* keys   = (const float*)d_in[1];
    const float* vals   = (const float*)d_in[2];
    const float* labels = (const float*)d_in[3];
    const int* hard_assign   = (const int*)d_in[4];
    const int* cached_groups = (const int*)d_in[5];
    const int* group_sizes   = (const int*)d_in[6];

    const int B = in_sizes[0] / DIMS;
    const int N = in_sizes[1] / DIMS;
    const int P = in_sizes[6];
    const int MAXG = in_sizes[5] / P;
    const int nslice = (MAXG + SLICE - 1) / SLICE;

    float* sims  = (float*)d_ws;                                // B*MAXG floats
    int* qcount  = (int*)((char*)d_ws + (size_t)B * MAXG * 4);  // P ints
    int* qlist   = qcount + P;                                  // P*B ints

    hipMemsetAsync(qcount, 0, P * sizeof(int), stream);

    bucket_kernel<<<(B + 255) / 256, 256, 0, stream>>>(hard_assign, qcount, qlist, B);

    score_kernel<<<P * nslice, NTHR, 0, stream>>>(
        query, keys, cached_groups, qcount, qlist, sims, B, N, MAXG, nslice);

    topk_gather_kernel<<<B, 256, 0, stream>>>(
        keys, vals, labels, hard_assign, cached_groups, group_sizes, sims,
        (float*)d_out, B, MAXG);
}

// Round 15
// 55.703 us; speedup vs baseline: 15.7268x; 1.0681x over previous
//
#include <hip/hip_runtime.h>

#define DIMS 128
#define KTOP 16
#define SMAX 2048     // max MAXG supported by top-k kernel
#define SLICE 64      // candidates per score block
#define CK 64         // s_keyT row stride in dwords (unpadded; 2-way = free)
#define QT 14         // queries per chunk (14 -> LDS <= 40 KB -> 4 blocks/CU)
#define CQ 14         // s_qT row stride in dwords
#define NTHR 128

__device__ __forceinline__ unsigned long long packsim(float v, int g) {
    unsigned u = __float_as_uint(v);
    u = (u & 0x80000000u) ? ~u : (u | 0x80000000u);
    return ((unsigned long long)u << 32) | (unsigned)(0xFFFFFFFFu - (unsigned)g);
}

// ------- Kernel 0: zero + bucket queries, single block (r5-proven) -------
__global__ __launch_bounds__(1024)
void bucket_kernel(const int* __restrict__ hard_assign,
                   int* __restrict__ qcount, int* __restrict__ qlist, int B, int P)
{
    const int t = threadIdx.x;
    for (int i = t; i < P; i += 1024) qcount[i] = 0;
    __syncthreads();
    for (int b = t; b < B; b += 1024) {
        const int p = hard_assign[b];
        const int slot = atomicAdd(&qcount[p], 1);
        qlist[(size_t)p * B + slot] = b;
    }
}

// ---- Kernel 1: register-tiled GEMM, 14q x 64c per block, 2q x 4c per thread ----
// LDS ~40.5 KB -> 4 blocks/CU resident (8 waves). Inner loop identical to r10.
__global__ __launch_bounds__(NTHR)
void score_kernel(const float* __restrict__ query,
                  const float* __restrict__ keys,
                  const int*   __restrict__ cached_groups,
                  const int*   __restrict__ qcount,
                  const int*   __restrict__ qlist,
                  float* __restrict__ sims,
                  int B, int N, int MAXG, int nslice)
{
    __shared__ float s_keyT[DIMS * CK];   // 32 KB, [d][c]
    __shared__ float s_qT[DIMS * CQ];     //  7 KB, [d][q]
    __shared__ float s_inv[SLICE];
    __shared__ int   s_g[SLICE];
    __shared__ int   s_qb[QT];

    const int p = blockIdx.x / nslice;
    const int s = blockIdx.x % nslice;
    const int cnt = qcount[p];
    if (cnt == 0) return;

    const int t = threadIdx.x;
    const int base = s * SLICE;
    const int* gp = cached_groups + (size_t)p * MAXG;
    const int* ql = qlist + (size_t)p * B;

    // ---- stage keys: 2 threads per candidate row (64 dims each) ----
    {
        const int r    = t >> 1;          // candidate 0..63
        const int half = t & 1;           // dim half
        const int cand = (base + r < MAXG) ? gp[base + r] : -1;
        if (half == 0) s_g[r] = cand;
        const int sf = cand < 0 ? 0 : (cand > N - 1 ? N - 1 : cand);
        const float* kr = keys + (size_t)sf * DIMS + half * 64;
        float ks = 0.0f;
        #pragma unroll
        for (int h = 0; h < 2; ++h) {     // 2 batches of 8 b128 loads (deep MLP)
            float4 v[8];
            #pragma unroll
            for (int i = 0; i < 8; ++i)
                v[i] = *(const float4*)(kr + h * 32 + i * 4);
            #pragma unroll
            for (int i = 0; i < 8; ++i) {
                const int d = half * 64 + h * 32 + i * 4;
                ks += v[i].x * v[i].x + v[i].y * v[i].y
                    + v[i].z * v[i].z + v[i].w * v[i].w;
                s_keyT[(d + 0) * CK + r] = v[i].x;
                s_keyT[(d + 1) * CK + r] = v[i].y;
                s_keyT[(d + 2) * CK + r] = v[i].z;
                s_keyT[(d + 3) * CK + r] = v[i].w;
            }
        }
        ks += __shfl_xor(ks, 1, 64);      // pair-reduce the two halves
        if (half == 0) s_inv[r] = 1.0f / fmaxf(sqrtf(ks), 1e-12f);
    }

    const int qg = t >> 4;                // 0..7; group 7 is a masked duplicate
    const int q0 = qg * 2;
    const int qr0 = (qg < 7) ? q0 : 0;    // clamp reads inside s_qT[.. QT)
    const int c0 = (t & 15) * 4;          // 0,4,..,60

    for (int qbase = 0; qbase < cnt; qbase += QT) {
        // ---- stage QT query rows transposed: thread (q=t&15 (<QT), dblk=t>>4) ----
        {
            const int q    = t & 15;
            const int dblk = t >> 4;      // 0..7, 16 dims each
            if (q < QT) {
                const int ii = qbase + q;
                const int sq = ql[(ii < cnt) ? ii : (cnt - 1)];   // dup tail, masked
                if (dblk == 0) s_qb[q] = sq;
                const float* qr = query + (size_t)sq * DIMS + dblk * 16;
                #pragma unroll
                for (int i = 0; i < 4; ++i) {
                    const float4 v = *(const float4*)(qr + i * 4);
                    const int d = dblk * 16 + i * 4;
                    s_qT[(d + 0) * CQ + q] = v.x;
                    s_qT[(d + 1) * CQ + q] = v.y;
                    s_qT[(d + 2) * CQ + q] = v.z;
                    s_qT[(d + 3) * CQ + q] = v.w;
                }
            }
        }
        __syncthreads();   // first iter: also covers key staging

        float acc[2][4];
        #pragma unroll
        for (int a = 0; a < 2; ++a)
            #pragma unroll
            for (int bb = 0; bb < 4; ++bb) acc[a][bb] = 0.0f;

        // A-read: b64 broadcast; B-read: b128 2-way (free)
        #pragma unroll 8
        for (int k = 0; k < DIMS; ++k) {
            const float2 aq = *(const float2*)&s_qT[k * CQ + qr0];
            const float4 bk = *(const float4*)&s_keyT[k * CK + c0];
            acc[0][0] += aq.x * bk.x; acc[0][1] += aq.x * bk.y;
            acc[0][2] += aq.x * bk.z; acc[0][3] += aq.x * bk.w;
            acc[1][0] += aq.y * bk.x; acc[1][1] += aq.y * bk.y;
            acc[1][2] += aq.y * bk.z; acc[1][3] += aq.y * bk.w;
        }

        // ---- epilogue: scale by key inv-norm, mask invalid, coalesced f4 ----
        const float4 inv = *(const float4*)&s_inv[c0];
        const int4   gv  = *(const int4*)&s_g[c0];
        #pragma unroll
        for (int qi = 0; qi < 2; ++qi) {
            const int ii = qbase + q0 + qi;
            if (qg < 7 && ii < cnt) {
                const int b = s_qb[q0 + qi];
                float4 o;
                o.x = (gv.x >= 0) ? acc[qi][0] * inv.x : -1.0e9f;
                o.y = (gv.y >= 0) ? acc[qi][1] * inv.y : -1.0e9f;
                o.z = (gv.z >= 0) ? acc[qi][2] * inv.z : -1.0e9f;
                o.w = (gv.w >= 0) ? acc[qi][3] * inv.w : -1.0e9f;
                float* dst = sims + (size_t)b * MAXG + base + c0;
                if (base + c0 + 3 < MAXG) {
                    *(float4*)dst = o;
                } else {
                    if (base + c0 + 0 < MAXG) dst[0] = o.x;
                    if (base + c0 + 1 < MAXG) dst[1] = o.y;
                    if (base + c0 + 2 < MAXG) dst[2] = o.z;
                }
            }
        }

        if (qbase + QT < cnt) __syncthreads();   // protect s_qT rewrite
    }
}

// ---------------- Kernel 2: top-16 per query + output gather ----------------
#define CASW(x,y) { if ((x) < (y)) { const unsigned long long _t = (x); (x) = (y); (y) = _t; } }

__global__ __launch_bounds__(256)
void topk_gather_kernel(const float* __restrict__ keys,
                        const float* __restrict__ vals,
                        const float* __restrict__ labels,
                        const int*   __restrict__ hard_assign,
                        const int*   __restrict__ cached_groups,
                        const int*   __restrict__ group_sizes,
                        const float* __restrict__ sims,
                        float* __restrict__ out,
                        int B, int MAXG)
{
    const int b = blockIdx.x, t = threadIdx.x;
    const int lane = t & 63, w = t >> 6;
    const int sub = t & 15, cg = t >> 4;

    __shared__ unsigned long long s_merge[64];
    __shared__ int s_wing[KTOP];

    const int p = hard_assign[b];
    const int grpsz = group_sizes[p];
    const bool normal = (grpsz >= KTOP);
    const int* gptr = cached_groups + (size_t)p * MAXG;
    const float* simrow = sims + (size_t)b * MAXG;

    // phase A: per-wave top-16 of 512, sorted-heads (keys globally unique)
    unsigned long long k0, k1, k2, k3, k4, k5, k6, k7;
    {
        #define LDK(j) ({ const int g = w * (SMAX / 4) + (j) * 64 + lane;          \
                          const float v = (g < MAXG) ? simrow[g] : -3.0e38f;       \
                          packsim(v, g); })
        k0 = LDK(0); k1 = LDK(1); k2 = LDK(2); k3 = LDK(3);
        k4 = LDK(4); k5 = LDK(5); k6 = LDK(6); k7 = LDK(7);
        #undef LDK
    }
    // Batcher odd-even mergesort, 19 comparators, descending
    CASW(k0,k1) CASW(k2,k3) CASW(k4,k5) CASW(k6,k7)
    CASW(k0,k2) CASW(k1,k3) CASW(k4,k6) CASW(k5,k7)
    CASW(k1,k2) CASW(k5,k6)
    CASW(k0,k4) CASW(k1,k5) CASW(k2,k6) CASW(k3,k7)
    CASW(k2,k4) CASW(k3,k5)
    CASW(k1,k2) CASW(k3,k4) CASW(k5,k6)

    #pragma unroll 1
    for (int r = 0; r < KTOP; ++r) {
        unsigned long long wm = k0;
        #pragma unroll
        for (int off = 1; off < 64; off <<= 1) {
            const unsigned long long o = __shfl_xor(wm, off, 64);
            wm = (o > wm) ? o : wm;
        }
        if (lane == 0) s_merge[w * KTOP + r] = wm;
        if (k0 == wm) {                  // unique keys -> exactly one winner
            k0 = k1; k1 = k2; k2 = k3; k3 = k4;
            k4 = k5; k5 = k6; k6 = k7; k7 = 0ull;
        }
    }
    __syncthreads();

    // phase B: wave 0 bitonic-sorts the 64 survivors (ascending); rank r at lane 63-r
    if (w == 0) {
        unsigned long long u = s_merge[lane];
        #pragma unroll
        for (int k = 2; k <= 64; k <<= 1) {
            #pragma unroll
            for (int j = k >> 1; j > 0; j >>= 1) {
                const unsigned long long o = __shfl_xor(u, j, 64);
                const bool low = (lane & j) == 0;
                const bool asc = (lane & k) == 0;
                const unsigned long long mn = (u < o) ? u : o;
                const unsigned long long mx = (u < o) ? o : u;
                u = (low == asc) ? mn : mx;
            }
        }
        if (lane >= 64 - KTOP)
            s_wing[63 - lane] = (int)(0xFFFFFFFFu - (unsigned)(u & 0xFFFFFFFFull));
    }
    __syncthreads();

    // outputs: group cg handles winner #cg
    const int g    = s_wing[cg];
    const int cand = gptr[g];
    const int idx  = cand < 0 ? 0 : cand;

    const size_t BK = (size_t)B * KTOP;
    float* out_nk = out;
    float* out_nv = out + BK * DIMS;
    float* out_nl = out + 2 * BK * DIMS;
    float* out_id = out_nl + BK;

    const size_t od = ((size_t)b * KTOP + cg) * DIMS + sub * 8;
    if (normal) {
        const float* kr = keys + (size_t)idx * DIMS + sub * 8;
        const float* vr = vals + (size_t)idx * DIMS + sub * 8;
        *(float4*)(out_nk + od)     = *(const float4*)(kr);
        *(float4*)(out_nk + od + 4) = *(const float4*)(kr + 4);
        *(float4*)(out_nv + od)     = *(const float4*)(vr);
        *(float4*)(out_nv + od + 4) = *(const float4*)(vr + 4);
        if (sub == 0) {
            out_nl[(size_t)b * KTOP + cg] = labels[idx];
            out_id[(size_t)b * KTOP + cg] = (float)idx;
        }
    } else {
        const float4 z = make_float4(0.f, 0.f, 0.f, 0.f);
        *(float4*)(out_nk + od)     = z;
        *(float4*)(out_nk + od + 4) = z;
        *(float4*)(out_nv + od)     = z;
        *(float4*)(out_nv + od + 4) = z;
        if (sub == 0) {
            out_nl[(size_t)b * KTOP + cg] = 0.0f;
            out_id[(size_t)b * KTOP + cg] = 0.0f;
        }
    }
}

extern "C" void kernel_launch(void* const* d_in, const int* in_sizes, int n_in,
                              void* d_out, int out_size, void* d_ws, size_t ws_size,
                              hipStream_t stream) {
    const float* query  = (const float*)d_in[0];
    const float* keys   = (const float*)d_in[1];
    const float* vals   = (const float*)d_in[2];
    const float* labels = (const float*)d_in[3];
    const int* hard_assign   = (const int*)d_in[4];
    const int* cached_groups = (const int*)d_in[5];
    const int* group_sizes   = (const int*)d_in[6];

    const int B = in_sizes[0] / DIMS;
    const int N = in_sizes[1] / DIMS;
    const int P = in_sizes[6];
    const int MAXG = in_sizes[5] / P;
    const int nslice = (MAXG + SLICE - 1) / SLICE;

    float* sims  = (float*)d_ws;                                // B*MAXG floats
    int* qcount  = (int*)((char*)d_ws + (size_t)B * MAXG * 4);  // P ints
    int* qlist   = qcount + P;                                  // P*B ints

    bucket_kernel<<<1, 1024, 0, stream>>>(hard_assign, qcount, qlist, B, P);

    score_kernel<<<P * nslice, NTHR, 0, stream>>>(
        query, keys, cached_groups, qcount, qlist, sims, B, N, MAXG, nslice);

    topk_gather_kernel<<<B, 256, 0, stream>>>(
        keys, vals, labels, hard_assign, cached_groups, group_sizes, sims,
        (float*)d_out, B, MAXG);
}

// Round 16
// 51.178 us; speedup vs baseline: 17.1171x; 1.0884x over previous
//
#include <hip/hip_runtime.h>

#define DIMS 128
#define KTOP 16
#define SMAX 2048     // max MAXG supported by top-k kernel
#define SLICE 64      // candidates per score block
#define CK 64         // s_keyT row stride in dwords (unpadded; 2-way = free)
#define QT 32         // queries per chunk (one chunk covers cnt<=32, ~+4 sigma)
#define CQ 32         // s_qT row stride in dwords
#define NTHR 256      // 4 waves: 2 stage keys, 2 stage queries, all compute

__device__ __forceinline__ unsigned long long packsim(float v, int g) {
    unsigned u = __float_as_uint(v);
    u = (u & 0x80000000u) ? ~u : (u | 0x80000000u);
    return ((unsigned long long)u << 32) | (unsigned)(0xFFFFFFFFu - (unsigned)g);
}

// ------- Kernel 0: zero + bucket queries, single block (r5-proven) -------
__global__ __launch_bounds__(1024)
void bucket_kernel(const int* __restrict__ hard_assign,
                   int* __restrict__ qcount, int* __restrict__ qlist, int B, int P)
{
    const int t = threadIdx.x;
    for (int i = t; i < P; i += 1024) qcount[i] = 0;
    __syncthreads();
    for (int b = t; b < B; b += 1024) {
        const int p = hard_assign[b];
        const int slot = atomicAdd(&qcount[p], 1);
        qlist[(size_t)p * B + slot] = b;
    }
}

// ---- Kernel 1: register-tiled GEMM, 32q x 64c per block, 2q x 4c per thread ----
// 256 threads (4 waves). LDS ~49.8 KB -> 2 blocks/CU (8 waves) under the
// ~128 KB usable-LDS budget. Key staging (waves 0-1) || query staging (waves 2-3).
__global__ __launch_bounds__(NTHR)
void score_kernel(const float* __restrict__ query,
                  const float* __restrict__ keys,
                  const int*   __restrict__ cached_groups,
                  const int*   __restrict__ qcount,
                  const int*   __restrict__ qlist,
                  float* __restrict__ sims,
                  int B, int N, int MAXG, int nslice)
{
    __shared__ float s_keyT[DIMS * CK];   // 32 KB, [d][c]
    __shared__ float s_qT[DIMS * CQ];     // 16 KB, [d][q]
    __shared__ float s_inv[SLICE];
    __shared__ int   s_g[SLICE];
    __shared__ int   s_qb[QT];

    const int p = blockIdx.x / nslice;
    const int s = blockIdx.x % nslice;
    const int cnt = qcount[p];
    if (cnt == 0) return;

    const int t = threadIdx.x;
    const int base = s * SLICE;
    const int* gp = cached_groups + (size_t)p * MAXG;
    const int* ql = qlist + (size_t)p * B;

    // ---- parallel staging: waves 0-1 keys, waves 2-3 first query chunk ----
    if (t < 128) {
        // keys: 2 threads per candidate row (64 dims each), r10-proven pattern
        const int r    = t >> 1;          // candidate 0..63
        const int half = t & 1;           // dim half
        const int cand = (base + r < MAXG) ? gp[base + r] : -1;
        if (half == 0) s_g[r] = cand;
        const int sf = cand < 0 ? 0 : (cand > N - 1 ? N - 1 : cand);
        const float* kr = keys + (size_t)sf * DIMS + half * 64;
        float ks = 0.0f;
        #pragma unroll
        for (int h = 0; h < 2; ++h) {     // 2 batches of 8 b128 loads (deep MLP)
            float4 v[8];
            #pragma unroll
            for (int i = 0; i < 8; ++i)
                v[i] = *(const float4*)(kr + h * 32 + i * 4);
            #pragma unroll
            for (int i = 0; i < 8; ++i) {
                const int d = half * 64 + h * 32 + i * 4;
                ks += v[i].x * v[i].x + v[i].y * v[i].y
                    + v[i].z * v[i].z + v[i].w * v[i].w;
                s_keyT[(d + 0) * CK + r] = v[i].x;
                s_keyT[(d + 1) * CK + r] = v[i].y;
                s_keyT[(d + 2) * CK + r] = v[i].z;
                s_keyT[(d + 3) * CK + r] = v[i].w;
            }
        }
        ks += __shfl_xor(ks, 1, 64);      // pair-reduce the two halves
        if (half == 0) s_inv[r] = 1.0f / fmaxf(sqrtf(ks), 1e-12f);
    } else {
        // queries: 4 threads per query row (32 dims each), chunk 0
        const int tq   = t - 128;
        const int q    = tq & 31;         // query slot 0..31
        const int dblk = tq >> 5;         // 0..3, 32 dims each
        const int sq   = ql[(q < cnt) ? q : (cnt - 1)];   // dup tail, store-masked
        if (dblk == 0) s_qb[q] = sq;
        const float* qr = query + (size_t)sq * DIMS + dblk * 32;
        #pragma unroll
        for (int i = 0; i < 8; ++i) {
            const float4 v = *(const float4*)(qr + i * 4);
            const int d = dblk * 32 + i * 4;
            s_qT[(d + 0) * CQ + q] = v.x;
            s_qT[(d + 1) * CQ + q] = v.y;
            s_qT[(d + 2) * CQ + q] = v.z;
            s_qT[(d + 3) * CQ + q] = v.w;
        }
    }
    __syncthreads();

    const int q0 = (t >> 4) * 2;          // 0,2,..,30
    const int c0 = (t & 15) * 4;          // 0,4,..,60

    for (int qbase = 0; ; ) {
        float acc[2][4];
        #pragma unroll
        for (int a = 0; a < 2; ++a)
            #pragma unroll
            for (int bb = 0; bb < 4; ++bb) acc[a][bb] = 0.0f;

        // A-read: b64 broadcast (4 addrs/wave); B-read: b128 2-way (free)
        #pragma unroll 8
        for (int k = 0; k < DIMS; ++k) {
            const float2 aq = *(const float2*)&s_qT[k * CQ + q0];
            const float4 bk = *(const float4*)&s_keyT[k * CK + c0];
            acc[0][0] += aq.x * bk.x; acc[0][1] += aq.x * bk.y;
            acc[0][2] += aq.x * bk.z; acc[0][3] += aq.x * bk.w;
            acc[1][0] += aq.y * bk.x; acc[1][1] += aq.y * bk.y;
            acc[1][2] += aq.y * bk.z; acc[1][3] += aq.y * bk.w;
        }

        // ---- epilogue: scale by key inv-norm, mask invalid, coalesced f4 ----
        const float4 inv = *(const float4*)&s_inv[c0];
        const int4   gv  = *(const int4*)&s_g[c0];
        #pragma unroll
        for (int qi = 0; qi < 2; ++qi) {
            const int ii = qbase + q0 + qi;
            if (ii < cnt) {
                const int b = s_qb[q0 + qi];
                float4 o;
                o.x = (gv.x >= 0) ? acc[qi][0] * inv.x : -1.0e9f;
                o.y = (gv.y >= 0) ? acc[qi][1] * inv.y : -1.0e9f;
                o.z = (gv.z >= 0) ? acc[qi][2] * inv.z : -1.0e9f;
                o.w = (gv.w >= 0) ? acc[qi][3] * inv.w : -1.0e9f;
                float* dst = sims + (size_t)b * MAXG + base + c0;
                if (base + c0 + 3 < MAXG) {
                    *(float4*)dst = o;
                } else {
                    if (base + c0 + 0 < MAXG) dst[0] = o.x;
                    if (base + c0 + 1 < MAXG) dst[1] = o.y;
                    if (base + c0 + 2 < MAXG) dst[2] = o.z;
                }
            }
        }

        qbase += QT;
        if (qbase >= cnt) break;          // common case: single chunk

        // rare path (cnt > 32): restage next query chunk
        __syncthreads();
        if (t >= 128) {
            const int tq   = t - 128;
            const int q    = tq & 31;
            const int dblk = tq >> 5;
            const int ii   = qbase + q;
            const int sq   = ql[(ii < cnt) ? ii : (cnt - 1)];
            if (dblk == 0) s_qb[q] = sq;
            const float* qr = query + (size_t)sq * DIMS + dblk * 32;
            #pragma unroll
            for (int i = 0; i < 8; ++i) {
                const float4 v = *(const float4*)(qr + i * 4);
                const int d = dblk * 32 + i * 4;
                s_qT[(d + 0) * CQ + q] = v.x;
                s_qT[(d + 1) * CQ + q] = v.y;
                s_qT[(d + 2) * CQ + q] = v.z;
                s_qT[(d + 3) * CQ + q] = v.w;
            }
        }
        __syncthreads();
    }
}

// ---------------- Kernel 2: top-16 per query + output gather ----------------
#define CASW(x,y) { if ((x) < (y)) { const unsigned long long _t = (x); (x) = (y); (y) = _t; } }

__global__ __launch_bounds__(256)
void topk_gather_kernel(const float* __restrict__ keys,
                        const float* __restrict__ vals,
                        const float* __restrict__ labels,
                        const int*   __restrict__ hard_assign,
                        const int*   __restrict__ cached_groups,
                        const int*   __restrict__ group_sizes,
                        const float* __restrict__ sims,
                        float* __restrict__ out,
                        int B, int MAXG)
{
    const int b = blockIdx.x, t = threadIdx.x;
    const int lane = t & 63, w = t >> 6;
    const int sub = t & 15, cg = t >> 4;

    __shared__ unsigned long long s_merge[64];
    __shared__ int s_wing[KTOP];

    const int p = hard_assign[b];
    const int grpsz = group_sizes[p];
    const bool normal = (grpsz >= KTOP);
    const int* gptr = cached_groups + (size_t)p * MAXG;
    const float* simrow = sims + (size_t)b * MAXG;

    // phase A: per-wave top-16 of 512, sorted-heads (keys globally unique)
    unsigned long long k0, k1, k2, k3, k4, k5, k6, k7;
    {
        #define LDK(j) ({ const int g = w * (SMAX / 4) + (j) * 64 + lane;          \
                          const float v = (g < MAXG) ? simrow[g] : -3.0e38f;       \
                          packsim(v, g); })
        k0 = LDK(0); k1 = LDK(1); k2 = LDK(2); k3 = LDK(3);
        k4 = LDK(4); k5 = LDK(5); k6 = LDK(6); k7 = LDK(7);
        #undef LDK
    }
    // Batcher odd-even mergesort, 19 comparators, descending
    CASW(k0,k1) CASW(k2,k3) CASW(k4,k5) CASW(k6,k7)
    CASW(k0,k2) CASW(k1,k3) CASW(k4,k6) CASW(k5,k7)
    CASW(k1,k2) CASW(k5,k6)
    CASW(k0,k4) CASW(k1,k5) CASW(k2,k6) CASW(k3,k7)
    CASW(k2,k4) CASW(k3,k5)
    CASW(k1,k2) CASW(k3,k4) CASW(k5,k6)

    #pragma unroll 1
    for (int r = 0; r < KTOP; ++r) {
        unsigned long long wm = k0;
        #pragma unroll
        for (int off = 1; off < 64; off <<= 1) {
            const unsigned long long o = __shfl_xor(wm, off, 64);
            wm = (o > wm) ? o : wm;
        }
        if (lane == 0) s_merge[w * KTOP + r] = wm;
        if (k0 == wm) {                  // unique keys -> exactly one winner
            k0 = k1; k1 = k2; k2 = k3; k3 = k4;
            k4 = k5; k5 = k6; k6 = k7; k7 = 0ull;
        }
    }
    __syncthreads();

    // phase B: wave 0 bitonic-sorts the 64 survivors (ascending); rank r at lane 63-r
    if (w == 0) {
        unsigned long long u = s_merge[lane];
        #pragma unroll
        for (int k = 2; k <= 64; k <<= 1) {
            #pragma unroll
            for (int j = k >> 1; j > 0; j >>= 1) {
                const unsigned long long o = __shfl_xor(u, j, 64);
                const bool low = (lane & j) == 0;
                const bool asc = (lane & k) == 0;
                const unsigned long long mn = (u < o) ? u : o;
                const unsigned long long mx = (u < o) ? o : u;
                u = (low == asc) ? mn : mx;
            }
        }
        if (lane >= 64 - KTOP)
            s_wing[63 - lane] = (int)(0xFFFFFFFFu - (unsigned)(u & 0xFFFFFFFFull));
    }
    __syncthreads();

    // outputs: group cg handles winner #cg
    const int g    = s_wing[cg];
    const int cand = gptr[g];
    const int idx  = cand < 0 ? 0 : cand;

    const size_t BK = (size_t)B * KTOP;
    float* out_nk = out;
    float* out_nv = out + BK * DIMS;
    float* out_nl = out + 2 * BK * DIMS;
    float* out_id = out_nl + BK;

    const size_t od = ((size_t)b * KTOP + cg) * DIMS + sub * 8;
    if (normal) {
        const float* kr = keys + (size_t)idx * DIMS + sub * 8;
        const float* vr = vals + (size_t)idx * DIMS + sub * 8;
        *(float4*)(out_nk + od)     = *(const float4*)(kr);
        *(float4*)(out_nk + od + 4) = *(const float4*)(kr + 4);
        *(float4*)(out_nv + od)     = *(const float4*)(vr);
        *(float4*)(out_nv + od + 4) = *(const float4*)(vr + 4);
        if (sub == 0) {
            out_nl[(size_t)b * KTOP + cg] = labels[idx];
            out_id[(size_t)b * KTOP + cg] = (float)idx;
        }
    } else {
        const float4 z = make_float4(0.f, 0.f, 0.f, 0.f);
        *(float4*)(out_nk + od)     = z;
        *(float4*)(out_nk + od + 4) = z;
        *(float4*)(out_nv + od)     = z;
        *(float4*)(out_nv + od + 4) = z;
        if (sub == 0) {
            out_nl[(size_t)b * KTOP + cg] = 0.0f;
            out_id[(size_t)b * KTOP + cg] = 0.0f;
        }
    }
}

extern "C" void kernel_launch(void* const* d_in, const int* in_sizes, int n_in,
                              void* d_out, int out_size, void* d_ws, size_t ws_size,
                              hipStream_t stream) {
    const float* query  = (const float*)d_in[0];
    const float* keys   = (const float*)d_in[1];
    const float* vals   = (const float*)d_in[2];
    const float* labels = (const float*)d_in[3];
    const int* hard_assign   = (const int*)d_in[4];
    const int* cached_groups = (const int*)d_in[5];
    const int* group_sizes   = (const int*)d_in[6];

    const int B = in_sizes[0] / DIMS;
    const int N = in_sizes[1] / DIMS;
    const int P = in_sizes[6];
    const int MAXG = in_sizes[5] / P;
    const int nslice = (MAXG + SLICE - 1) / SLICE;

    float* sims  = (float*)d_ws;                                // B*MAXG floats
    int* qcount  = (int*)((char*)d_ws + (size_t)B * MAXG * 4);  // P ints
    int* qlist   = qcount + P;                                  // P*B ints

    bucket_kernel<<<1, 1024, 0, stream>>>(hard_assign, qcount, qlist, B, P);

    score_kernel<<<P * nslice, NTHR, 0, stream>>>(
        query, keys, cached_groups, qcount, qlist, sims, B, N, MAXG, nslice);

    topk_gather_kernel<<<B, 256, 0, stream>>>(
        keys, vals, labels, hard_assign, cached_groups, group_sizes, sims,
        (float*)d_out, B, MAXG);
}